// Round 9
// baseline (934.628 us; speedup 1.0000x reference)
//
#include <hip/hip_runtime.h>

typedef __bf16 bf16x8 __attribute__((ext_vector_type(8)));
typedef float f32x4 __attribute__((ext_vector_type(4)));

#define B_ 16
#define T_ 1024
#define D_ 512
#define S_ 12
#define C_ 11
static constexpr int P_TOTAL = 2148960;  // 176 * (12*1024 - 78)

__device__ __host__ inline constexpr int pred_base(int i) {
  return C_ * B_ * (T_ * i - (i * (i + 1)) / 2);
}

__device__ inline unsigned short f2bf(float f) {
  unsigned int u = __float_as_uint(f);
  u += 0x7FFF + ((u >> 16) & 1);   // round-to-nearest-even
  return (unsigned short)(u >> 16);
}

__device__ inline void gld16(const void* g, void* l) {
  __builtin_amdgcn_global_load_lds(
      (const __attribute__((address_space(1))) void*)g,
      (__attribute__((address_space(3))) void*)l, 16, 0, 0);
}

// ---------------- prep: W [i][o][s] f32 -> wt [s][o][i] bf16 ----------------
__global__ __launch_bounds__(256) void prep_w(const float* __restrict__ W,
                                              unsigned short* __restrict__ wt) {
  __shared__ unsigned short tile[32][33][12];
  const int i0 = blockIdx.x * 32, o0 = blockIdx.y * 32;
#pragma unroll
  for (int q = 0; q < 48; ++q) {
    int idx = threadIdx.x + q * 256;
    int ii = idx / 384, rem = idx % 384;
    tile[ii][rem / 12][rem % 12] =
        f2bf(W[(size_t)(i0 + ii) * 6144 + (size_t)o0 * 12 + rem]);
  }
  __syncthreads();
#pragma unroll
  for (int q = 0; q < 48; ++q) {
    int idx = threadIdx.x + q * 256;
    int ss = idx / 1024, rem = idx % 1024;
    int oo = rem / 32, ii = rem % 32;
    wt[(size_t)ss * (D_ * D_) + (size_t)(o0 + oo) * D_ + (i0 + ii)] = tile[ii][oo][ss];
  }
}

// -- prep: transpose [b][D][T] f32 -> [b][T][D] bf16, both x and y (z=0..31) --
__global__ __launch_bounds__(256) void prep_t2(const float* __restrict__ xin,
                                               const float* __restrict__ yin,
                                               unsigned short* __restrict__ xo,
                                               unsigned short* __restrict__ yo) {
  __shared__ float tile[32][33];
  const int t0 = blockIdx.x * 32;
  const int d0 = blockIdx.y * 32;
  const int b = blockIdx.z & 15;
  const float* in = (blockIdx.z < 16) ? xin : yin;
  unsigned short* ob = (blockIdx.z < 16) ? xo : yo;
  const float* ib = in + (size_t)b * D_ * T_;
  const int r = threadIdx.x / 32, c = threadIdx.x % 32;
#pragma unroll
  for (int p = 0; p < 4; ++p) {
    int rr = r + p * 8;
    tile[rr][c] = ib[(size_t)(d0 + rr) * T_ + t0 + c];
  }
  __syncthreads();
  unsigned short* op = ob + (size_t)b * T_ * D_;
#pragma unroll
  for (int p = 0; p < 4; ++p) {
    int rr = r + p * 8;
    op[(size_t)(t0 + rr) * D_ + d0 + c] = f2bf(tile[c][rr]);
  }
}

// ---------------- labels ----------------
__global__ void labels_k(float* __restrict__ lab) {
  int k = blockIdx.x * 256 + threadIdx.x;
  if (k >= P_TOTAL) return;
  int i = 0;
#pragma unroll
  for (int q = 1; q < 12; ++q)
    if (k >= pred_base(q)) i = q;
  int rel = k - pred_base(i);
  int len = T_ - 1 - i;
  lab[k] = (rel < B_ * len) ? 1.0f : 0.0f;
}

// ---- GEMM: xp[bl][s][t][o] = xb[m][i] * wt[s][o][i] + bias[o] --------------
// R6 8-phase structure shrunk to BK=32: 2 bufs x 32KB = 64KB LDS so TWO
// blocks co-reside per CU (de-phased pipes overlap, m114). 256x256 tile,
// 8 waves 2Mx4N, 4 quadrant-phases/ks, counted vmcnt(1)@p0 / vmcnt(2)@p3,
// XOR swizzle depth (row>>1)&3 over 4 slots (2-way = free), persistent tiles.
__global__ __launch_bounds__(512, 4) void gemm_xp(
    const unsigned short* __restrict__ xb,   // [bc*1024][512]
    const unsigned short* __restrict__ wt,   // [12][512 o][512 i]
    const float* __restrict__ bias,          // [512]
    unsigned short* __restrict__ xp,         // [bc][12][1024][512]
    int tiles, int mtiles) {
  __shared__ char ldsb[65536];   // 2 bufs x (A[256][32] 16KB + B[256][32] 16KB)
  const int tid = threadIdx.x;
  const int w = tid >> 6, l = tid & 63;
  const int gm = w >> 2, gn = w & 3;
  const int fr = l & 15, sgrp = l >> 4;

  // staging: 1 gld16/thread per 8KB half-tile; linear LDS dest, source col
  // inverse-swizzled (rule #21).
  const int dox = tid * 16;                  // byte offset within 8KB half
  const int rloc = dox >> 6;                 // local row 0..127 (64B rows)
  const int sc = (dox >> 4) & 3;
  const int sco = rloc * 1024 + ((sc ^ ((rloc >> 1) & 3)) << 4);

  auto stageH = [&](const char* panel, int ks, int half, int base) {
    gld16(panel + half * 131072 + ks * 64 + sco, ldsb + base + half * 8192 + dox);
  };

  // fragment byte-offsets (A region [0,16K), B at +16384), swizzled
  const int csw = (sgrp ^ ((fr >> 1) & 3)) << 4;
  int aOff[2][4], bOff[2][2];
#pragma unroll
  for (int mh = 0; mh < 2; ++mh)
#pragma unroll
    for (int fm = 0; fm < 4; ++fm)
      aOff[mh][fm] = (gm * 64 + mh * 128 + fm * 16 + fr) * 64 + csw;
#pragma unroll
  for (int nh = 0; nh < 2; ++nh)
#pragma unroll
    for (int fn = 0; fn < 2; ++fn)
      bOff[nh][fn] = 16384 + (gn * 32 + nh * 128 + fn * 16 + fr) * 64 + csw;

  auto ldf = [&](int off) -> bf16x8 { return *(const bf16x8*)(ldsb + off); };

  auto decode = [&](int t, const unsigned short*& Ag, const unsigned short*& Bg,
                    int& n0v, int& miv, int& siv) {
    miv = t % mtiles;
    int rest = t / mtiles;
    int ni = rest & 1;
    siv = rest >> 1;
    Ag = xb + (size_t)(miv * 256) * D_;
    Bg = wt + ((size_t)siv * D_ + ni * 256) * D_;
    n0v = ni * 256;
  };

  int ti = blockIdx.x;
  if (ti >= tiles) return;
  const unsigned short *Ag, *Bg, *Agn = nullptr, *Bgn = nullptr;
  int n0, mi, si, n0n, min_, sin_;
  decode(ti, Ag, Bg, n0, mi, si);
  int tin = ti + gridDim.x;
  bool hasNext = tin < tiles;
  if (hasNext) decode(tin, Agn, Bgn, n0n, min_, sin_);

#define BAR()  asm volatile("" ::: "memory"); __builtin_amdgcn_s_barrier(); \
               asm volatile("" ::: "memory")

  // prologue: 4 halves of ks=0 into buf0; confirm h0 pair, keep h1 in flight
  stageH((const char*)Ag, 0, 0, 0);
  stageH((const char*)Bg, 0, 0, 16384);
  stageH((const char*)Ag, 0, 1, 0);
  stageH((const char*)Bg, 0, 1, 16384);
  asm volatile("s_waitcnt vmcnt(2)" ::: "memory");
  BAR();

  while (true) {
    f32x4 acc[8][4];   // [mh*4+fm][nh*2+fn]
#pragma unroll
    for (int a = 0; a < 8; ++a)
#pragma unroll
      for (int bq = 0; bq < 4; ++bq)
#pragma unroll
        for (int e = 0; e < 4; ++e) acc[a][bq][e] = 0.f;

    float bv[2][2];
#pragma unroll
    for (int nh = 0; nh < 2; ++nh)
#pragma unroll
      for (int fn = 0; fn < 2; ++fn)
        bv[nh][fn] = bias[n0 + gn * 32 + nh * 128 + fn * 16 + fr];

#pragma unroll
    for (int ks = 0; ks < 16; ++ks) {
      const int bufB = (ks & 1) * 32768;
      const int nbufB = bufB ^ 32768;
      const bool st = (ks < 15) || hasNext;
      const char* pA = (ks < 15) ? (const char*)Ag : (const char*)Agn;
      const char* pB = (ks < 15) ? (const char*)Bg : (const char*)Bgn;
      const int kn = (ks < 15) ? ks + 1 : 0;
      bf16x8 af[4], b0[2], b1[2];

      // ============ phase 0 : q(mh0, nh0) ============
#pragma unroll
      for (int fm = 0; fm < 4; ++fm) af[fm] = ldf(bufB + aOff[0][fm]);
#pragma unroll
      for (int fn = 0; fn < 2; ++fn) b0[fn] = ldf(bufB + bOff[0][fn]);
      if (st) {
        stageH(pA, kn, 0, nbufB);
        asm volatile("s_waitcnt vmcnt(1)" ::: "memory");
      } else {
        asm volatile("s_waitcnt vmcnt(0)" ::: "memory");
      }
      BAR();
      __builtin_amdgcn_s_setprio(1);
#pragma unroll
      for (int fm = 0; fm < 4; ++fm)
#pragma unroll
        for (int fn = 0; fn < 2; ++fn)
          acc[fm][fn] = __builtin_amdgcn_mfma_f32_16x16x32_bf16(
              af[fm], b0[fn], acc[fm][fn], 0, 0, 0);
      __builtin_amdgcn_s_setprio(0);
      BAR();

      // ============ phase 1 : q(mh0, nh1) ============
#pragma unroll
      for (int fn = 0; fn < 2; ++fn) b1[fn] = ldf(bufB + bOff[1][fn]);
      if (st) stageH(pB, kn, 0, nbufB + 16384);
      BAR();
      __builtin_amdgcn_s_setprio(1);
#pragma unroll
      for (int fm = 0; fm < 4; ++fm)
#pragma unroll
        for (int fn = 0; fn < 2; ++fn)
          acc[fm][2 + fn] = __builtin_amdgcn_mfma_f32_16x16x32_bf16(
              af[fm], b1[fn], acc[fm][2 + fn], 0, 0, 0);
      __builtin_amdgcn_s_setprio(0);
      BAR();

      // ============ phase 2 : q(mh1, nh1) ============
#pragma unroll
      for (int fm = 0; fm < 4; ++fm) af[fm] = ldf(bufB + aOff[1][fm]);
      if (st) stageH(pA, kn, 1, nbufB);
      BAR();
      __builtin_amdgcn_s_setprio(1);
#pragma unroll
      for (int fm = 0; fm < 4; ++fm)
#pragma unroll
        for (int fn = 0; fn < 2; ++fn)
          acc[4 + fm][2 + fn] = __builtin_amdgcn_mfma_f32_16x16x32_bf16(
              af[fm], b1[fn], acc[4 + fm][2 + fn], 0, 0, 0);
      __builtin_amdgcn_s_setprio(0);
      BAR();

      // ============ phase 3 : q(mh1, nh0) ============
      if (st) stageH(pB, kn, 1, nbufB + 16384);
      BAR();
      __builtin_amdgcn_s_setprio(1);
#pragma unroll
      for (int fm = 0; fm < 4; ++fm)
#pragma unroll
        for (int fn = 0; fn < 2; ++fn)
          acc[4 + fm][fn] = __builtin_amdgcn_mfma_f32_16x16x32_bf16(
              af[fm], b0[fn], acc[4 + fm][fn], 0, 0, 0);
      __builtin_amdgcn_s_setprio(0);
      if (st) asm volatile("s_waitcnt vmcnt(2)" ::: "memory");
      BAR();
    }

    // epilogue: bias + bf16 store (next tile's in-flight stages ride through)
#pragma unroll
    for (int mh = 0; mh < 2; ++mh) {
#pragma unroll
      for (int fm = 0; fm < 4; ++fm) {
#pragma unroll
        for (int r = 0; r < 4; ++r) {
          int m = mi * 256 + gm * 64 + mh * 128 + fm * 16 + sgrp * 4 + r;
          int bl = m >> 10, t = m & 1023;
          size_t orow = (((size_t)bl * S_ + si) * T_ + t) * D_;
#pragma unroll
          for (int nh = 0; nh < 2; ++nh)
#pragma unroll
            for (int fn = 0; fn < 2; ++fn) {
              int o = n0 + gn * 32 + nh * 128 + fn * 16 + fr;
              xp[orow + o] = f2bf(acc[mh * 4 + fm][nh * 2 + fn][r] + bv[nh][fn]);
            }
        }
      }
    }

    if (!hasNext) break;
    ti = tin;
    Ag = Agn; Bg = Bgn; n0 = n0n; mi = min_; si = sin_;
    tin = ti + gridDim.x;
    hasNext = tin < tiles;
    if (hasNext) decode(tin, Agn, Bgn, n0n, min_, sin_);
  }
#undef BAR
}

// ---- predictions: one wave per (b, 4 x tt); 12x11 tiles via 16 MFMAs each --
__global__ __launch_bounds__(256) void pred_k(
    const unsigned short* __restrict__ xp,   // [bc][12][1024][512]
    const unsigned short* __restrict__ yT,   // [16][1024][512]
    const int* __restrict__ negs,            // [16][10][1024]
    float* __restrict__ preds, int b0) {
  const int w = threadIdx.x >> 6, l = threadIdx.x & 63;
  const int bl = blockIdx.y;
  const int b = b0 + bl;
  const int fr = l & 15;
  const int koff = (l >> 4) * 8;

  const unsigned short* arow[4];
  const unsigned short* brow[4];
  int tts[4];
#pragma unroll
  for (int q = 0; q < 4; ++q) {
    int tt = blockIdx.x * 4 + w + q * 256;
    tts[q] = tt;
    int t = tt - 1 - fr;
    bool av = (fr < S_) && (t >= 0);
    arow[q] = xp + (((size_t)bl * S_ + (av ? fr : 0)) * T_ + (av ? t : 0)) * D_;
    int j = tt;
    if (fr >= 1 && fr <= 10) j = negs[b * (10 * T_) + (fr - 1) * T_ + tt];
    brow[q] = yT + ((size_t)b * T_ + j) * D_;
  }

  f32x4 acc[4];
#pragma unroll
  for (int q = 0; q < 4; ++q)
#pragma unroll
    for (int e = 0; e < 4; ++e) acc[q][e] = 0.f;

#pragma unroll
  for (int kk = 0; kk < 16; ++kk) {
#pragma unroll
    for (int q = 0; q < 4; ++q) {
      bf16x8 a = *(const bf16x8*)(arow[q] + kk * 32 + koff);
      bf16x8 bb = *(const bf16x8*)(brow[q] + kk * 32 + koff);
      acc[q] = __builtin_amdgcn_mfma_f32_16x16x32_bf16(a, bb, acc[q], 0, 0, 0);
    }
  }

#pragma unroll
  for (int q = 0; q < 4; ++q) {
#pragma unroll
    for (int r = 0; r < 4; ++r) {
      int ii = (l >> 4) * 4 + r;
      int to = tts[q] - 1 - ii;
      if (ii < S_ && fr < C_ && tts[q] >= 1 && to >= 0) {
        int len = T_ - 1 - ii;
        preds[pred_base(ii) + ((size_t)fr * B_ + b) * len + to] = acc[q][r];
      }
    }
  }
}

extern "C" void kernel_launch(void* const* d_in, const int* in_sizes, int n_in,
                              void* d_out, int out_size, void* d_ws, size_t ws_size,
                              hipStream_t stream) {
  (void)in_sizes; (void)n_in; (void)out_size;
  const float* x = (const float*)d_in[0];
  const float* y = (const float*)d_in[1];
  const float* W = (const float*)d_in[2];
  const float* bias = (const float*)d_in[3];
  const int* negs = (const int*)d_in[4];
  float* out = (float*)d_out;
  char* ws = (char*)d_ws;

  unsigned short* wt = (unsigned short*)ws;                         // 6,291,456 B
  unsigned short* xb = (unsigned short*)(ws + 6291456);             // 16,777,216 B
  unsigned short* yT = (unsigned short*)(ws + 6291456 + 16777216);  // 16,777,216 B
  unsigned short* xp = (unsigned short*)(ws + 6291456 + 2 * 16777216);
  const size_t fixed = 6291456 + (size_t)2 * 16777216;              // 39,845,888
  const size_t xp_per_b = (size_t)S_ * T_ * D_ * 2;                 // 12,582,912
  int nb = 1;
  if (ws_size > fixed) {
    size_t cap = (ws_size - fixed) / xp_per_b;
    nb = cap < 1 ? 1 : (cap > 16 ? 16 : (int)cap);
  }

  hipLaunchKernelGGL(prep_w, dim3(16, 16), dim3(256), 0, stream, W, wt);
  hipLaunchKernelGGL(prep_t2, dim3(32, 16, 32), dim3(256), 0, stream, x, y, xb, yT);
  hipLaunchKernelGGL(labels_k, dim3((P_TOTAL + 255) / 256), dim3(256), 0, stream,
                     out + P_TOTAL);

  for (int b0 = 0; b0 < B_; b0 += nb) {
    int bc = (B_ - b0) < nb ? (B_ - b0) : nb;
    int tiles = bc * 4 * 2 * 12;              // 256x256 tiles
    int grid = tiles < 512 ? tiles : 512;     // 2 blocks/CU when full
    hipLaunchKernelGGL(gemm_xp, dim3(grid), dim3(512), 0, stream,
                       xb + (size_t)b0 * T_ * D_, wt, bias, xp,
                       tiles, bc * 4);
    hipLaunchKernelGGL(pred_k, dim3(64, bc), dim3(256), 0, stream,
                       xp, yT, negs, out, b0);
  }
}

// Round 10
// 211.793 us; speedup vs baseline: 4.4129x; 4.4129x over previous
//
#include <hip/hip_runtime.h>

typedef __bf16 bf16x8 __attribute__((ext_vector_type(8)));
typedef float f32x4 __attribute__((ext_vector_type(4)));

#define B_ 16
#define T_ 1024
#define D_ 512
#define S_ 12
#define C_ 11
static constexpr int P_TOTAL = 2148960;  // 176 * (12*1024 - 78)

__device__ __host__ inline constexpr int pred_base(int i) {
  return C_ * B_ * (T_ * i - (i * (i + 1)) / 2);
}

__device__ inline unsigned short f2bf(float f) {
  unsigned int u = __float_as_uint(f);
  u += 0x7FFF + ((u >> 16) & 1);   // round-to-nearest-even
  return (unsigned short)(u >> 16);
}

__device__ inline void gld16(const void* g, void* l) {
  __builtin_amdgcn_global_load_lds(
      (const __attribute__((address_space(1))) void*)g,
      (__attribute__((address_space(3))) void*)l, 16, 0, 0);
}

// ---------------- prep: W [i][o][s] f32 -> wt [s][o][i] bf16 ----------------
__global__ __launch_bounds__(256) void prep_w(const float* __restrict__ W,
                                              unsigned short* __restrict__ wt) {
  __shared__ unsigned short tile[32][33][12];
  const int i0 = blockIdx.x * 32, o0 = blockIdx.y * 32;
#pragma unroll
  for (int q = 0; q < 48; ++q) {
    int idx = threadIdx.x + q * 256;
    int ii = idx / 384, rem = idx % 384;
    tile[ii][rem / 12][rem % 12] =
        f2bf(W[(size_t)(i0 + ii) * 6144 + (size_t)o0 * 12 + rem]);
  }
  __syncthreads();
#pragma unroll
  for (int q = 0; q < 48; ++q) {
    int idx = threadIdx.x + q * 256;
    int ss = idx / 1024, rem = idx % 1024;
    int oo = rem / 32, ii = rem % 32;
    wt[(size_t)ss * (D_ * D_) + (size_t)(o0 + oo) * D_ + (i0 + ii)] = tile[ii][oo][ss];
  }
}

// -- prep: transpose [b][D][T] f32 -> [b][T][D] bf16, both x and y (z=0..31) --
__global__ __launch_bounds__(256) void prep_t2(const float* __restrict__ xin,
                                               const float* __restrict__ yin,
                                               unsigned short* __restrict__ xo,
                                               unsigned short* __restrict__ yo) {
  __shared__ float tile[32][33];
  const int t0 = blockIdx.x * 32;
  const int d0 = blockIdx.y * 32;
  const int b = blockIdx.z & 15;
  const float* in = (blockIdx.z < 16) ? xin : yin;
  unsigned short* ob = (blockIdx.z < 16) ? xo : yo;
  const float* ib = in + (size_t)b * D_ * T_;
  const int r = threadIdx.x / 32, c = threadIdx.x % 32;
#pragma unroll
  for (int p = 0; p < 4; ++p) {
    int rr = r + p * 8;
    tile[rr][c] = ib[(size_t)(d0 + rr) * T_ + t0 + c];
  }
  __syncthreads();
  unsigned short* op = ob + (size_t)b * T_ * D_;
#pragma unroll
  for (int p = 0; p < 4; ++p) {
    int rr = r + p * 8;
    op[(size_t)(t0 + rr) * D_ + d0 + c] = f2bf(tile[c][rr]);
  }
}

// ---- GEMM: xp[bl][s][t][o] = xb[m][i] * wt[s][o][i] + bias[o] --------------
// Proven R6 structure: 8-phase m201-style, 256x256 tile, BK=64, 8 waves,
// 2 LDS buffers (128 KiB), counted vmcnt, XOR swizzle, setprio.
// At 845 TF this matches the verified m248 ceiling (848 TF) for grouped
// 256^2 K<=1024 GEMM — schedule work concluded.
__global__ __launch_bounds__(512, 1) void gemm_xp(
    const unsigned short* __restrict__ xb,   // [bc*1024][512]
    const unsigned short* __restrict__ wt,   // [12][512 o][512 i]
    const float* __restrict__ bias,          // [512]
    unsigned short* __restrict__ xp,         // [bc][12][1024][512]
    int tiles, int mtiles) {
  __shared__ char ldsb[131072];  // 2 bufs x (A[256][64] 32KB + B[256][64] 32KB)
  const int tid = threadIdx.x;
  const int w = tid >> 6, l = tid & 63;
  const int gm = w >> 2, gn = w & 3;
  const int fr = l & 15, sgrp = l >> 4;

  // ---- staging constants (linear LDS dest, inverse-swizzled global src) ----
  const int dox0 = tid * 16, dox1 = tid * 16 + 8192;
  const int rl0 = dox0 >> 7, rl1 = dox1 >> 7;         // local rows 0..127
  const int col = dox0 & 127;
  const int sco0 = rl0 * 1024 + (col ^ ((rl0 & 7) << 4));
  const int sco1 = rl1 * 1024 + (col ^ ((rl1 & 7) << 4));

  auto stageH = [&](const char* panel, int ks, int half, int ldsBase) {
    const char* s = panel + half * 131072 + ks * 128;
    char* d = ldsb + ldsBase + half * 16384;
    gld16(s + sco0, d + dox0);
    gld16(s + sco1, d + dox1);
  };

  // ---- fragment read constants ----
  const int sw = (fr & 7) << 4;
  const int colk0 = (sgrp * 16) ^ sw;        // kk=0
  const int colk1 = (64 + sgrp * 16) ^ sw;   // kk=1
  const int aRowB = (gm * 64 + fr) * 128;    // byte row base in A tile
  const int bRowB = 32768 + (gn * 32 + fr) * 128;

  auto ldf = [&](int off) -> bf16x8 {
    return *(const bf16x8*)(ldsb + off);
  };

  auto decode = [&](int t, const unsigned short*& Ag, const unsigned short*& Bg,
                    int& n0v, int& miv, int& siv) {
    miv = t % mtiles;
    int rest = t / mtiles;
    int ni = rest & 1;
    siv = rest >> 1;
    Ag = xb + (size_t)(miv * 256) * D_;
    Bg = wt + ((size_t)siv * D_ + ni * 256) * D_;
    n0v = ni * 256;
  };

  int ti = blockIdx.x;
  if (ti >= tiles) return;
  const unsigned short *Ag, *Bg, *Agn = nullptr, *Bgn = nullptr;
  int n0, mi, si, n0n, min_, sin_;
  decode(ti, Ag, Bg, n0, mi, si);
  int tin = ti + gridDim.x;
  bool hasNext = tin < tiles;
  if (hasNext) decode(tin, Agn, Bgn, n0n, min_, sin_);

#define BAR()  asm volatile("" ::: "memory"); __builtin_amdgcn_s_barrier(); \
               asm volatile("" ::: "memory")

  // prologue: all 4 halves of K-step 0 into buf0
  stageH((const char*)Ag, 0, 0, 0);
  stageH((const char*)Bg, 0, 0, 32768);
  stageH((const char*)Ag, 0, 1, 0);
  stageH((const char*)Bg, 0, 1, 32768);
  asm volatile("s_waitcnt vmcnt(4)" ::: "memory");
  BAR();

  while (true) {
    f32x4 acc[8][4];   // [mh*4+fm][nh*2+fn]
#pragma unroll
    for (int a = 0; a < 8; ++a)
#pragma unroll
      for (int bq = 0; bq < 4; ++bq)
#pragma unroll
        for (int e = 0; e < 4; ++e) acc[a][bq][e] = 0.f;

    float bv[2][2];
#pragma unroll
    for (int nh = 0; nh < 2; ++nh)
#pragma unroll
      for (int fn = 0; fn < 2; ++fn)
        bv[nh][fn] = bias[n0 + gn * 32 + nh * 128 + fn * 16 + fr];

#pragma unroll
    for (int ks = 0; ks < 8; ++ks) {
      const int bufB = (ks & 1) * 65536;
      const int nbufB = bufB ^ 65536;
      const bool st = (ks < 7) || hasNext;
      const char* pA = (ks < 7) ? (const char*)Ag : (const char*)Agn;
      const char* pB = (ks < 7) ? (const char*)Bg : (const char*)Bgn;
      const int kn = (ks < 7) ? ks + 1 : 0;
      bf16x8 af[2][4], b0[2][2], b1[2][2];

      // ================= phase 0 : q(mh0, nh0) =================
#pragma unroll
      for (int fm = 0; fm < 4; ++fm) {
        af[0][fm] = ldf(bufB + aRowB + fm * 2048 + colk0);
        af[1][fm] = ldf(bufB + aRowB + fm * 2048 + colk1);
      }
#pragma unroll
      for (int fn = 0; fn < 2; ++fn) {
        b0[0][fn] = ldf(bufB + bRowB + fn * 2048 + colk0);
        b0[1][fn] = ldf(bufB + bRowB + fn * 2048 + colk1);
      }
      if (st) {
        stageH(pA, kn, 0, nbufB);
        asm volatile("s_waitcnt vmcnt(2)" ::: "memory");
      } else {
        asm volatile("s_waitcnt vmcnt(0)" ::: "memory");
      }
      BAR();
      __builtin_amdgcn_s_setprio(1);
#pragma unroll
      for (int kk = 0; kk < 2; ++kk)
#pragma unroll
        for (int fm = 0; fm < 4; ++fm)
#pragma unroll
          for (int fn = 0; fn < 2; ++fn)
            acc[fm][fn] = __builtin_amdgcn_mfma_f32_16x16x32_bf16(
                af[kk][fm], b0[kk][fn], acc[fm][fn], 0, 0, 0);
      __builtin_amdgcn_s_setprio(0);
      BAR();

      // ================= phase 1 : q(mh0, nh1) =================
#pragma unroll
      for (int fn = 0; fn < 2; ++fn) {
        b1[0][fn] = ldf(bufB + bRowB + 16384 + fn * 2048 + colk0);
        b1[1][fn] = ldf(bufB + bRowB + 16384 + fn * 2048 + colk1);
      }
      if (st) stageH(pB, kn, 0, nbufB + 32768);
      BAR();
      __builtin_amdgcn_s_setprio(1);
#pragma unroll
      for (int kk = 0; kk < 2; ++kk)
#pragma unroll
        for (int fm = 0; fm < 4; ++fm)
#pragma unroll
          for (int fn = 0; fn < 2; ++fn)
            acc[fm][2 + fn] = __builtin_amdgcn_mfma_f32_16x16x32_bf16(
                af[kk][fm], b1[kk][fn], acc[fm][2 + fn], 0, 0, 0);
      __builtin_amdgcn_s_setprio(0);
      BAR();

      // ================= phase 2 : q(mh1, nh1) =================
#pragma unroll
      for (int fm = 0; fm < 4; ++fm) {
        af[0][fm] = ldf(bufB + aRowB + 16384 + fm * 2048 + colk0);
        af[1][fm] = ldf(bufB + aRowB + 16384 + fm * 2048 + colk1);
      }
      if (st) stageH(pA, kn, 1, nbufB);
      BAR();
      __builtin_amdgcn_s_setprio(1);
#pragma unroll
      for (int kk = 0; kk < 2; ++kk)
#pragma unroll
        for (int fm = 0; fm < 4; ++fm)
#pragma unroll
          for (int fn = 0; fn < 2; ++fn)
            acc[4 + fm][2 + fn] = __builtin_amdgcn_mfma_f32_16x16x32_bf16(
                af[kk][fm], b1[kk][fn], acc[4 + fm][2 + fn], 0, 0, 0);
      __builtin_amdgcn_s_setprio(0);
      BAR();

      // ================= phase 3 : q(mh1, nh0) =================
      if (st) stageH(pB, kn, 1, nbufB + 32768);
      BAR();
      __builtin_amdgcn_s_setprio(1);
#pragma unroll
      for (int kk = 0; kk < 2; ++kk)
#pragma unroll
        for (int fm = 0; fm < 4; ++fm)
#pragma unroll
          for (int fn = 0; fn < 2; ++fn)
            acc[4 + fm][fn] = __builtin_amdgcn_mfma_f32_16x16x32_bf16(
                af[kk][fm], b0[kk][fn], acc[4 + fm][fn], 0, 0, 0);
      __builtin_amdgcn_s_setprio(0);
      if (st) asm volatile("s_waitcnt vmcnt(4)" ::: "memory");
      BAR();
    }

    // epilogue: bias + bf16 store (staging for next tile rides through)
#pragma unroll
    for (int mh = 0; mh < 2; ++mh) {
#pragma unroll
      for (int fm = 0; fm < 4; ++fm) {
#pragma unroll
        for (int r = 0; r < 4; ++r) {
          int m = mi * 256 + gm * 64 + mh * 128 + fm * 16 + sgrp * 4 + r;
          int bl = m >> 10, t = m & 1023;
          size_t orow = (((size_t)bl * S_ + si) * T_ + t) * D_;
#pragma unroll
          for (int nh = 0; nh < 2; ++nh)
#pragma unroll
            for (int fn = 0; fn < 2; ++fn) {
              int o = n0 + gn * 32 + nh * 128 + fn * 16 + fr;
              xp[orow + o] = f2bf(acc[mh * 4 + fm][nh * 2 + fn][r] + bv[nh][fn]);
            }
        }
      }
    }

    if (!hasNext) break;
    ti = tin;
    Ag = Agn; Bg = Bgn; n0 = n0n; mi = min_; si = sin_;
    tin = ti + gridDim.x;
    hasNext = tin < tiles;
    if (hasNext) decode(tin, Agn, Bgn, n0n, min_, sin_);
  }
#undef BAR
}

// ---- predictions: one wave per (b, 2 x tt); 12x11 tiles via 16 MFMAs each --
// 2x blocks vs R6 (more TLP for the latency-bound L3 gather) + labels tail.
__global__ __launch_bounds__(256) void pred_k(
    const unsigned short* __restrict__ xp,   // [bc][12][1024][512]
    const unsigned short* __restrict__ yT,   // [16][1024][512]
    const int* __restrict__ negs,            // [16][10][1024]
    float* __restrict__ preds, int b0, int do_labels) {
  const int w = threadIdx.x >> 6, l = threadIdx.x & 63;
  const int bl = blockIdx.y;
  const int b = b0 + bl;
  const int fr = l & 15;
  const int koff = (l >> 4) * 8;

  const unsigned short* arow[2];
  const unsigned short* brow[2];
  int tts[2];
#pragma unroll
  for (int q = 0; q < 2; ++q) {
    int tt = blockIdx.x * 4 + w + q * 512;
    tts[q] = tt;
    int t = tt - 1 - fr;
    bool av = (fr < S_) && (t >= 0);
    arow[q] = xp + (((size_t)bl * S_ + (av ? fr : 0)) * T_ + (av ? t : 0)) * D_;
    int j = tt;
    if (fr >= 1 && fr <= 10) j = negs[b * (10 * T_) + (fr - 1) * T_ + tt];
    brow[q] = yT + ((size_t)b * T_ + j) * D_;
  }

  f32x4 acc[2];
#pragma unroll
  for (int q = 0; q < 2; ++q)
#pragma unroll
    for (int e = 0; e < 4; ++e) acc[q][e] = 0.f;

#pragma unroll
  for (int kk = 0; kk < 16; ++kk) {
#pragma unroll
    for (int q = 0; q < 2; ++q) {
      bf16x8 a = *(const bf16x8*)(arow[q] + kk * 32 + koff);
      bf16x8 bb = *(const bf16x8*)(brow[q] + kk * 32 + koff);
      acc[q] = __builtin_amdgcn_mfma_f32_16x16x32_bf16(a, bb, acc[q], 0, 0, 0);
    }
  }

#pragma unroll
  for (int q = 0; q < 2; ++q) {
#pragma unroll
    for (int r = 0; r < 4; ++r) {
      int ii = (l >> 4) * 4 + r;
      int to = tts[q] - 1 - ii;
      if (ii < S_ && fr < C_ && tts[q] >= 1 && to >= 0) {
        int len = T_ - 1 - ii;
        preds[pred_base(ii) + ((size_t)fr * B_ + b) * len + to] = acc[q][r];
      }
    }
  }

  // ---- labels tail (grid-stride over out[P_TOTAL .. 2*P_TOTAL)) ----
  if (do_labels) {
    float* lab = preds + P_TOTAL;
    const int stride = gridDim.x * gridDim.y * 256;
    int k = (blockIdx.y * gridDim.x + blockIdx.x) * 256 + threadIdx.x;
    for (; k < P_TOTAL; k += stride) {
      int i = 0;
#pragma unroll
      for (int qq = 1; qq < 12; ++qq)
        if (k >= pred_base(qq)) i = qq;
      int rel = k - pred_base(i);
      int len = T_ - 1 - i;
      lab[k] = (rel < B_ * len) ? 1.0f : 0.0f;
    }
  }
}

extern "C" void kernel_launch(void* const* d_in, const int* in_sizes, int n_in,
                              void* d_out, int out_size, void* d_ws, size_t ws_size,
                              hipStream_t stream) {
  (void)in_sizes; (void)n_in; (void)out_size;
  const float* x = (const float*)d_in[0];
  const float* y = (const float*)d_in[1];
  const float* W = (const float*)d_in[2];
  const float* bias = (const float*)d_in[3];
  const int* negs = (const int*)d_in[4];
  float* out = (float*)d_out;
  char* ws = (char*)d_ws;

  unsigned short* wt = (unsigned short*)ws;                         // 6,291,456 B
  unsigned short* xb = (unsigned short*)(ws + 6291456);             // 16,777,216 B
  unsigned short* yT = (unsigned short*)(ws + 6291456 + 16777216);  // 16,777,216 B
  unsigned short* xp = (unsigned short*)(ws + 6291456 + 2 * 16777216);
  const size_t fixed = 6291456 + (size_t)2 * 16777216;              // 39,845,888
  const size_t xp_per_b = (size_t)S_ * T_ * D_ * 2;                 // 12,582,912
  int nb = 1;
  if (ws_size > fixed) {
    size_t cap = (ws_size - fixed) / xp_per_b;
    nb = cap < 1 ? 1 : (cap > 16 ? 16 : (int)cap);
  }

  hipLaunchKernelGGL(prep_w, dim3(16, 16), dim3(256), 0, stream, W, wt);
  hipLaunchKernelGGL(prep_t2, dim3(32, 16, 32), dim3(256), 0, stream, x, y, xb, yT);

  for (int b0 = 0; b0 < B_; b0 += nb) {
    int bc = (B_ - b0) < nb ? (B_ - b0) : nb;
    int tiles = bc * 4 * 2 * 12;              // 256x256 tiles
    int grid = tiles < 256 ? tiles : 256;
    hipLaunchKernelGGL(gemm_xp, dim3(grid), dim3(512), 0, stream,
                       xb + (size_t)b0 * T_ * D_, wt, bias, xp,
                       tiles, bc * 4);
    hipLaunchKernelGGL(pred_k, dim3(128, bc), dim3(256), 0, stream,
                       xp, yT, negs, out, b0, (int)(b0 == 0));
  }
}

// Round 11
// 201.848 us; speedup vs baseline: 4.6304x; 1.0493x over previous
//
#include <hip/hip_runtime.h>

typedef __bf16 bf16x8 __attribute__((ext_vector_type(8)));
typedef __bf16 bf16x2 __attribute__((ext_vector_type(2)));
typedef float f32x4 __attribute__((ext_vector_type(4)));

#define B_ 16
#define T_ 1024
#define D_ 512
#define S_ 12
#define C_ 11
static constexpr int P_TOTAL = 2148960;  // 176 * (12*1024 - 78)

__device__ __host__ inline constexpr int pred_base(int i) {
  return C_ * B_ * (T_ * i - (i * (i + 1)) / 2);
}

__device__ inline unsigned short f2bf(float f) {
  unsigned int u = __float_as_uint(f);
  u += 0x7FFF + ((u >> 16) & 1);   // round-to-nearest-even
  return (unsigned short)(u >> 16);
}

// low-5-bit storage permutation on the second-stage contraction dim
// (o of xp / d of x,y / i of W): natural v=(fn*16+fr) -> stored (fr<<1)|fn.
// Verified end-to-end in R7 (passed, absmax 0.5). Dots are invariant since
// xp/yT (and xb/wt) share the same permutation.
__device__ inline int perm5(int v) { return ((v & 15) << 1) | (v >> 4); }

__device__ inline void gld16(const void* g, void* l) {
  __builtin_amdgcn_global_load_lds(
      (const __attribute__((address_space(1))) void*)g,
      (__attribute__((address_space(3))) void*)l, 16, 0, 0);
}

// ---------------- prep: W [i][o][s] f32 -> wt [s][o][perm(i)] bf16 ----------
__global__ __launch_bounds__(256) void prep_w(const float* __restrict__ W,
                                              unsigned short* __restrict__ wt) {
  __shared__ unsigned short tile[32][33][12];
  const int i0 = blockIdx.x * 32, o0 = blockIdx.y * 32;
#pragma unroll
  for (int q = 0; q < 48; ++q) {
    int idx = threadIdx.x + q * 256;
    int ii = idx / 384, rem = idx % 384;
    tile[ii][rem / 12][rem % 12] =
        f2bf(W[(size_t)(i0 + ii) * 6144 + (size_t)o0 * 12 + rem]);
  }
  __syncthreads();
#pragma unroll
  for (int q = 0; q < 48; ++q) {
    int idx = threadIdx.x + q * 256;
    int ss = idx / 1024, rem = idx % 1024;
    int oo = rem / 32, ii = rem % 32;
    wt[(size_t)ss * (D_ * D_) + (size_t)(o0 + oo) * D_ + i0 + perm5(ii)] =
        tile[ii][oo][ss];
  }
}

// -- prep: transpose [b][D][T] f32 -> [b][T][perm(D)] bf16 (x and y, z=0..31) -
__global__ __launch_bounds__(256) void prep_t2(const float* __restrict__ xin,
                                               const float* __restrict__ yin,
                                               unsigned short* __restrict__ xo,
                                               unsigned short* __restrict__ yo) {
  __shared__ float tile[32][33];
  const int t0 = blockIdx.x * 32;
  const int d0 = blockIdx.y * 32;
  const int b = blockIdx.z & 15;
  const float* in = (blockIdx.z < 16) ? xin : yin;
  unsigned short* ob = (blockIdx.z < 16) ? xo : yo;
  const float* ib = in + (size_t)b * D_ * T_;
  const int r = threadIdx.x / 32, c = threadIdx.x % 32;
#pragma unroll
  for (int p = 0; p < 4; ++p) {
    int rr = r + p * 8;
    tile[rr][c] = ib[(size_t)(d0 + rr) * T_ + t0 + c];
  }
  __syncthreads();
  unsigned short* op = ob + (size_t)b * T_ * D_;
#pragma unroll
  for (int p = 0; p < 4; ++p) {
    int rr = r + p * 8;
    op[(size_t)(t0 + rr) * D_ + d0 + perm5(c)] = f2bf(tile[c][rr]);
  }
}

// ---- GEMM: xp[bl][s][t][perm(o)] = xb[m][i'] * wt[s][o][i'] + bias[o] ------
// Proven R6 K-loop (845 TF = m248 ceiling for this regime). Epilogue packs
// (fn0,fn1) pairs (adjacent under perm5) via native bf16 casts -> cvt_pk,
// 64 coalesced dword stores per thread (was 128 scalar shorts + 128 f2bf).
__global__ __launch_bounds__(512, 1) void gemm_xp(
    const unsigned short* __restrict__ xb,   // [bc*1024][512']
    const unsigned short* __restrict__ wt,   // [12][512 o][512 i']
    const float* __restrict__ bias,          // [512]
    unsigned short* __restrict__ xp,         // [bc][12][1024][512']
    int tiles, int mtiles) {
  __shared__ char ldsb[131072];  // 2 bufs x (A[256][64] 32KB + B[256][64] 32KB)
  const int tid = threadIdx.x;
  const int w = tid >> 6, l = tid & 63;
  const int gm = w >> 2, gn = w & 3;
  const int fr = l & 15, sgrp = l >> 4;

  // ---- staging constants (linear LDS dest, inverse-swizzled global src) ----
  const int dox0 = tid * 16, dox1 = tid * 16 + 8192;
  const int rl0 = dox0 >> 7, rl1 = dox1 >> 7;         // local rows 0..127
  const int col = dox0 & 127;
  const int sco0 = rl0 * 1024 + (col ^ ((rl0 & 7) << 4));
  const int sco1 = rl1 * 1024 + (col ^ ((rl1 & 7) << 4));

  auto stageH = [&](const char* panel, int ks, int half, int ldsBase) {
    const char* s = panel + half * 131072 + ks * 128;
    char* d = ldsb + ldsBase + half * 16384;
    gld16(s + sco0, d + dox0);
    gld16(s + sco1, d + dox1);
  };

  // ---- fragment read constants ----
  const int sw = (fr & 7) << 4;
  const int colk0 = (sgrp * 16) ^ sw;        // kk=0
  const int colk1 = (64 + sgrp * 16) ^ sw;   // kk=1
  const int aRowB = (gm * 64 + fr) * 128;    // byte row base in A tile
  const int bRowB = 32768 + (gn * 32 + fr) * 128;

  auto ldf = [&](int off) -> bf16x8 {
    return *(const bf16x8*)(ldsb + off);
  };

  auto decode = [&](int t, const unsigned short*& Ag, const unsigned short*& Bg,
                    int& n0v, int& miv, int& siv) {
    miv = t % mtiles;
    int rest = t / mtiles;
    int ni = rest & 1;
    siv = rest >> 1;
    Ag = xb + (size_t)(miv * 256) * D_;
    Bg = wt + ((size_t)siv * D_ + ni * 256) * D_;
    n0v = ni * 256;
  };

  int ti = blockIdx.x;
  if (ti >= tiles) return;
  const unsigned short *Ag, *Bg, *Agn = nullptr, *Bgn = nullptr;
  int n0, mi, si, n0n, min_, sin_;
  decode(ti, Ag, Bg, n0, mi, si);
  int tin = ti + gridDim.x;
  bool hasNext = tin < tiles;
  if (hasNext) decode(tin, Agn, Bgn, n0n, min_, sin_);

#define BAR()  asm volatile("" ::: "memory"); __builtin_amdgcn_s_barrier(); \
               asm volatile("" ::: "memory")

  // prologue: all 4 halves of K-step 0 into buf0
  stageH((const char*)Ag, 0, 0, 0);
  stageH((const char*)Bg, 0, 0, 32768);
  stageH((const char*)Ag, 0, 1, 0);
  stageH((const char*)Bg, 0, 1, 32768);
  asm volatile("s_waitcnt vmcnt(4)" ::: "memory");
  BAR();

  while (true) {
    f32x4 acc[8][4];   // [mh*4+fm][nh*2+fn]
#pragma unroll
    for (int a = 0; a < 8; ++a)
#pragma unroll
      for (int bq = 0; bq < 4; ++bq)
#pragma unroll
        for (int e = 0; e < 4; ++e) acc[a][bq][e] = 0.f;

    float bv[2][2];
#pragma unroll
    for (int nh = 0; nh < 2; ++nh)
#pragma unroll
      for (int fn = 0; fn < 2; ++fn)
        bv[nh][fn] = bias[n0 + gn * 32 + nh * 128 + fn * 16 + fr];

#pragma unroll
    for (int ks = 0; ks < 8; ++ks) {
      const int bufB = (ks & 1) * 65536;
      const int nbufB = bufB ^ 65536;
      const bool st = (ks < 7) || hasNext;
      const char* pA = (ks < 7) ? (const char*)Ag : (const char*)Agn;
      const char* pB = (ks < 7) ? (const char*)Bg : (const char*)Bgn;
      const int kn = (ks < 7) ? ks + 1 : 0;
      bf16x8 af[2][4], b0[2][2], b1[2][2];

      // ================= phase 0 : q(mh0, nh0) =================
#pragma unroll
      for (int fm = 0; fm < 4; ++fm) {
        af[0][fm] = ldf(bufB + aRowB + fm * 2048 + colk0);
        af[1][fm] = ldf(bufB + aRowB + fm * 2048 + colk1);
      }
#pragma unroll
      for (int fn = 0; fn < 2; ++fn) {
        b0[0][fn] = ldf(bufB + bRowB + fn * 2048 + colk0);
        b0[1][fn] = ldf(bufB + bRowB + fn * 2048 + colk1);
      }
      if (st) {
        stageH(pA, kn, 0, nbufB);
        asm volatile("s_waitcnt vmcnt(2)" ::: "memory");
      } else {
        asm volatile("s_waitcnt vmcnt(0)" ::: "memory");
      }
      BAR();
      __builtin_amdgcn_s_setprio(1);
#pragma unroll
      for (int kk = 0; kk < 2; ++kk)
#pragma unroll
        for (int fm = 0; fm < 4; ++fm)
#pragma unroll
          for (int fn = 0; fn < 2; ++fn)
            acc[fm][fn] = __builtin_amdgcn_mfma_f32_16x16x32_bf16(
                af[kk][fm], b0[kk][fn], acc[fm][fn], 0, 0, 0);
      __builtin_amdgcn_s_setprio(0);
      BAR();

      // ================= phase 1 : q(mh0, nh1) =================
#pragma unroll
      for (int fn = 0; fn < 2; ++fn) {
        b1[0][fn] = ldf(bufB + bRowB + 16384 + fn * 2048 + colk0);
        b1[1][fn] = ldf(bufB + bRowB + 16384 + fn * 2048 + colk1);
      }
      if (st) stageH(pB, kn, 0, nbufB + 32768);
      BAR();
      __builtin_amdgcn_s_setprio(1);
#pragma unroll
      for (int kk = 0; kk < 2; ++kk)
#pragma unroll
        for (int fm = 0; fm < 4; ++fm)
#pragma unroll
          for (int fn = 0; fn < 2; ++fn)
            acc[fm][2 + fn] = __builtin_amdgcn_mfma_f32_16x16x32_bf16(
                af[kk][fm], b1[kk][fn], acc[fm][2 + fn], 0, 0, 0);
      __builtin_amdgcn_s_setprio(0);
      BAR();

      // ================= phase 2 : q(mh1, nh1) =================
#pragma unroll
      for (int fm = 0; fm < 4; ++fm) {
        af[0][fm] = ldf(bufB + aRowB + 16384 + fm * 2048 + colk0);
        af[1][fm] = ldf(bufB + aRowB + 16384 + fm * 2048 + colk1);
      }
      if (st) stageH(pA, kn, 1, nbufB);
      BAR();
      __builtin_amdgcn_s_setprio(1);
#pragma unroll
      for (int kk = 0; kk < 2; ++kk)
#pragma unroll
        for (int fm = 0; fm < 4; ++fm)
#pragma unroll
          for (int fn = 0; fn < 2; ++fn)
            acc[4 + fm][2 + fn] = __builtin_amdgcn_mfma_f32_16x16x32_bf16(
                af[kk][fm], b1[kk][fn], acc[4 + fm][2 + fn], 0, 0, 0);
      __builtin_amdgcn_s_setprio(0);
      BAR();

      // ================= phase 3 : q(mh1, nh0) =================
      if (st) stageH(pB, kn, 1, nbufB + 32768);
      BAR();
      __builtin_amdgcn_s_setprio(1);
#pragma unroll
      for (int kk = 0; kk < 2; ++kk)
#pragma unroll
        for (int fm = 0; fm < 4; ++fm)
#pragma unroll
          for (int fn = 0; fn < 2; ++fn)
            acc[4 + fm][fn] = __builtin_amdgcn_mfma_f32_16x16x32_bf16(
                af[kk][fm], b0[kk][fn], acc[4 + fm][fn], 0, 0, 0);
      __builtin_amdgcn_s_setprio(0);
      if (st) asm volatile("s_waitcnt vmcnt(4)" ::: "memory");
      BAR();
    }

    // epilogue: bias + packed bf16x2 dword stores at perm5 positions.
    // stored o' = n0 + nh*128 + gm-free: gn*32 + 2*fr + fn  (adjacent pair).
#pragma unroll
    for (int mh = 0; mh < 2; ++mh) {
#pragma unroll
      for (int fm = 0; fm < 4; ++fm) {
#pragma unroll
        for (int r = 0; r < 4; ++r) {
          int m = mi * 256 + gm * 64 + mh * 128 + fm * 16 + sgrp * 4 + r;
          int bl = m >> 10, t = m & 1023;
          size_t orow = (((size_t)bl * S_ + si) * T_ + t) * D_;
#pragma unroll
          for (int nh = 0; nh < 2; ++nh) {
            bf16x2 pk;
            pk[0] = (__bf16)(acc[mh * 4 + fm][nh * 2 + 0][r] + bv[nh][0]);
            pk[1] = (__bf16)(acc[mh * 4 + fm][nh * 2 + 1][r] + bv[nh][1]);
            int op = n0 + nh * 128 + gn * 32 + 2 * fr;
            *(bf16x2*)(xp + orow + op) = pk;
          }
        }
      }
    }

    if (!hasNext) break;
    ti = tin;
    Ag = Agn; Bg = Bgn; n0 = n0n; mi = min_; si = sin_;
    tin = ti + gridDim.x;
    hasNext = tin < tiles;
    if (hasNext) decode(tin, Agn, Bgn, n0n, min_, sin_);
  }
#undef BAR
}

// ---- predictions: one wave per (b, 2 x tt); 12x11 tiles via 16 MFMAs each --
// Reads xp and yT in (matching) perm5 stored order -> dot invariant.
__global__ __launch_bounds__(256) void pred_k(
    const unsigned short* __restrict__ xp,   // [bc][12][1024][512']
    const unsigned short* __restrict__ yT,   // [16][1024][512']
    const int* __restrict__ negs,            // [16][10][1024]
    float* __restrict__ preds, int b0, int do_labels) {
  const int w = threadIdx.x >> 6, l = threadIdx.x & 63;
  const int bl = blockIdx.y;
  const int b = b0 + bl;
  const int fr = l & 15;
  const int koff = (l >> 4) * 8;

  const unsigned short* arow[2];
  const unsigned short* brow[2];
  int tts[2];
#pragma unroll
  for (int q = 0; q < 2; ++q) {
    int tt = blockIdx.x * 4 + w + q * 512;
    tts[q] = tt;
    int t = tt - 1 - fr;
    bool av = (fr < S_) && (t >= 0);
    arow[q] = xp + (((size_t)bl * S_ + (av ? fr : 0)) * T_ + (av ? t : 0)) * D_;
    int j = tt;
    if (fr >= 1 && fr <= 10) j = negs[b * (10 * T_) + (fr - 1) * T_ + tt];
    brow[q] = yT + ((size_t)b * T_ + j) * D_;
  }

  f32x4 acc[2];
#pragma unroll
  for (int q = 0; q < 2; ++q)
#pragma unroll
    for (int e = 0; e < 4; ++e) acc[q][e] = 0.f;

#pragma unroll
  for (int kk = 0; kk < 16; ++kk) {
#pragma unroll
    for (int q = 0; q < 2; ++q) {
      bf16x8 a = *(const bf16x8*)(arow[q] + kk * 32 + koff);
      bf16x8 bb = *(const bf16x8*)(brow[q] + kk * 32 + koff);
      acc[q] = __builtin_amdgcn_mfma_f32_16x16x32_bf16(a, bb, acc[q], 0, 0, 0);
    }
  }

#pragma unroll
  for (int q = 0; q < 2; ++q) {
#pragma unroll
    for (int r = 0; r < 4; ++r) {
      int ii = (l >> 4) * 4 + r;
      int to = tts[q] - 1 - ii;
      if (ii < S_ && fr < C_ && tts[q] >= 1 && to >= 0) {
        int len = T_ - 1 - ii;
        preds[pred_base(ii) + ((size_t)fr * B_ + b) * len + to] = acc[q][r];
      }
    }
  }

  // ---- labels tail (grid-stride over out[P_TOTAL .. 2*P_TOTAL)) ----
  if (do_labels) {
    float* lab = preds + P_TOTAL;
    const int stride = gridDim.x * gridDim.y * 256;
    int k = (blockIdx.y * gridDim.x + blockIdx.x) * 256 + threadIdx.x;
    for (; k < P_TOTAL; k += stride) {
      int i = 0;
#pragma unroll
      for (int qq = 1; qq < 12; ++qq)
        if (k >= pred_base(qq)) i = qq;
      int rel = k - pred_base(i);
      int len = T_ - 1 - i;
      lab[k] = (rel < B_ * len) ? 1.0f : 0.0f;
    }
  }
}

extern "C" void kernel_launch(void* const* d_in, const int* in_sizes, int n_in,
                              void* d_out, int out_size, void* d_ws, size_t ws_size,
                              hipStream_t stream) {
  (void)in_sizes; (void)n_in; (void)out_size;
  const float* x = (const float*)d_in[0];
  const float* y = (const float*)d_in[1];
  const float* W = (const float*)d_in[2];
  const float* bias = (const float*)d_in[3];
  const int* negs = (const int*)d_in[4];
  float* out = (float*)d_out;
  char* ws = (char*)d_ws;

  unsigned short* wt = (unsigned short*)ws;                         // 6,291,456 B
  unsigned short* xb = (unsigned short*)(ws + 6291456);             // 16,777,216 B
  unsigned short* yT = (unsigned short*)(ws + 6291456 + 16777216);  // 16,777,216 B
  unsigned short* xp = (unsigned short*)(ws + 6291456 + 2 * 16777216);
  const size_t fixed = 6291456 + (size_t)2 * 16777216;              // 39,845,888
  const size_t xp_per_b = (size_t)S_ * T_ * D_ * 2;                 // 12,582,912
  int nb = 1;
  if (ws_size > fixed) {
    size_t cap = (ws_size - fixed) / xp_per_b;
    nb = cap < 1 ? 1 : (cap > 16 ? 16 : (int)cap);
  }

  hipLaunchKernelGGL(prep_w, dim3(16, 16), dim3(256), 0, stream, W, wt);
  hipLaunchKernelGGL(prep_t2, dim3(32, 16, 32), dim3(256), 0, stream, x, y, xb, yT);

  for (int b0 = 0; b0 < B_; b0 += nb) {
    int bc = (B_ - b0) < nb ? (B_ - b0) : nb;
    int tiles = bc * 4 * 2 * 12;              // 256x256 tiles
    int grid = tiles < 256 ? tiles : 256;
    hipLaunchKernelGGL(gemm_xp, dim3(grid), dim3(512), 0, stream,
                       xb + (size_t)b0 * T_ * D_, wt, bias, xp,
                       tiles, bc * 4);
    hipLaunchKernelGGL(pred_k, dim3(128, bc), dim3(256), 0, stream,
                       xp, yT, negs, out, b0, (int)(b0 == 0));
  }
}

// Round 12
// 194.144 us; speedup vs baseline: 4.8141x; 1.0397x over previous
//
#include <hip/hip_runtime.h>

typedef __bf16 bf16x8 __attribute__((ext_vector_type(8)));
typedef __bf16 bf16x2 __attribute__((ext_vector_type(2)));
typedef float f32x4 __attribute__((ext_vector_type(4)));

#define B_ 16
#define T_ 1024
#define D_ 512
#define S_ 12
#define C_ 11
static constexpr int P_TOTAL = 2148960;  // 176 * (12*1024 - 78)

__device__ __host__ inline constexpr int pred_base(int i) {
  return C_ * B_ * (T_ * i - (i * (i + 1)) / 2);
}

__device__ inline unsigned short f2bf(float f) {
  unsigned int u = __float_as_uint(f);
  u += 0x7FFF + ((u >> 16) & 1);   // round-to-nearest-even
  return (unsigned short)(u >> 16);
}

// low-5-bit storage permutation on the second-stage contraction dim
// (o of xp / d of x,y / i of W): natural v=(fn*16+fr) -> stored (fr<<1)|fn.
__device__ inline int perm5(int v) { return ((v & 15) << 1) | (v >> 4); }

__device__ inline void gld16(const void* g, void* l) {
  __builtin_amdgcn_global_load_lds(
      (const __attribute__((address_space(1))) void*)g,
      (__attribute__((address_space(3))) void*)l, 16, 0, 0);
}

// ---------------- prep: W [i][o][s] f32 -> wt [s][o][perm(i)] bf16 ----------
__global__ __launch_bounds__(256) void prep_w(const float* __restrict__ W,
                                              unsigned short* __restrict__ wt) {
  __shared__ unsigned short tile[32][33][12];
  const int i0 = blockIdx.x * 32, o0 = blockIdx.y * 32;
#pragma unroll
  for (int q = 0; q < 48; ++q) {
    int idx = threadIdx.x + q * 256;
    int ii = idx / 384, rem = idx % 384;
    tile[ii][rem / 12][rem % 12] =
        f2bf(W[(size_t)(i0 + ii) * 6144 + (size_t)o0 * 12 + rem]);
  }
  __syncthreads();
#pragma unroll
  for (int q = 0; q < 48; ++q) {
    int idx = threadIdx.x + q * 256;
    int ss = idx / 1024, rem = idx % 1024;
    int oo = rem / 32, ii = rem % 32;
    wt[(size_t)ss * (D_ * D_) + (size_t)(o0 + oo) * D_ + i0 + perm5(ii)] =
        tile[ii][oo][ss];
  }
}

// -- prep: transpose [b][D][T] f32 -> [b][T][perm(D)] bf16 (x and y, z=0..31) -
__global__ __launch_bounds__(256) void prep_t2(const float* __restrict__ xin,
                                               const float* __restrict__ yin,
                                               unsigned short* __restrict__ xo,
                                               unsigned short* __restrict__ yo) {
  __shared__ float tile[32][33];
  const int t0 = blockIdx.x * 32;
  const int d0 = blockIdx.y * 32;
  const int b = blockIdx.z & 15;
  const float* in = (blockIdx.z < 16) ? xin : yin;
  unsigned short* ob = (blockIdx.z < 16) ? xo : yo;
  const float* ib = in + (size_t)b * D_ * T_;
  const int r = threadIdx.x / 32, c = threadIdx.x % 32;
#pragma unroll
  for (int p = 0; p < 4; ++p) {
    int rr = r + p * 8;
    tile[rr][c] = ib[(size_t)(d0 + rr) * T_ + t0 + c];
  }
  __syncthreads();
  unsigned short* op = ob + (size_t)b * T_ * D_;
#pragma unroll
  for (int p = 0; p < 4; ++p) {
    int rr = r + p * 8;
    op[(size_t)(t0 + rr) * D_ + d0 + perm5(c)] = f2bf(tile[c][rr]);
  }
}

// ---- GEMM: xp[bl][s][t][perm(o)] = xb[m][i'] * wt[s][o][i'] + bias[o] ------
// R11 proven: 8-phase 256x256 / BK=64 / 8-wave, counted vmcnt, XOR swizzle,
// setprio, packed bf16x2 epilogue. 925 TF effective — concluded.
__global__ __launch_bounds__(512, 1) void gemm_xp(
    const unsigned short* __restrict__ xb,   // [bc*1024][512']
    const unsigned short* __restrict__ wt,   // [12][512 o][512 i']
    const float* __restrict__ bias,          // [512]
    unsigned short* __restrict__ xp,         // [bc][12][1024][512']
    int tiles, int mtiles) {
  __shared__ char ldsb[131072];  // 2 bufs x (A[256][64] 32KB + B[256][64] 32KB)
  const int tid = threadIdx.x;
  const int w = tid >> 6, l = tid & 63;
  const int gm = w >> 2, gn = w & 3;
  const int fr = l & 15, sgrp = l >> 4;

  const int dox0 = tid * 16, dox1 = tid * 16 + 8192;
  const int rl0 = dox0 >> 7, rl1 = dox1 >> 7;
  const int col = dox0 & 127;
  const int sco0 = rl0 * 1024 + (col ^ ((rl0 & 7) << 4));
  const int sco1 = rl1 * 1024 + (col ^ ((rl1 & 7) << 4));

  auto stageH = [&](const char* panel, int ks, int half, int ldsBase) {
    const char* s = panel + half * 131072 + ks * 128;
    char* d = ldsb + ldsBase + half * 16384;
    gld16(s + sco0, d + dox0);
    gld16(s + sco1, d + dox1);
  };

  const int sw = (fr & 7) << 4;
  const int colk0 = (sgrp * 16) ^ sw;
  const int colk1 = (64 + sgrp * 16) ^ sw;
  const int aRowB = (gm * 64 + fr) * 128;
  const int bRowB = 32768 + (gn * 32 + fr) * 128;

  auto ldf = [&](int off) -> bf16x8 {
    return *(const bf16x8*)(ldsb + off);
  };

  auto decode = [&](int t, const unsigned short*& Ag, const unsigned short*& Bg,
                    int& n0v, int& miv, int& siv) {
    miv = t % mtiles;
    int rest = t / mtiles;
    int ni = rest & 1;
    siv = rest >> 1;
    Ag = xb + (size_t)(miv * 256) * D_;
    Bg = wt + ((size_t)siv * D_ + ni * 256) * D_;
    n0v = ni * 256;
  };

  int ti = blockIdx.x;
  if (ti >= tiles) return;
  const unsigned short *Ag, *Bg, *Agn = nullptr, *Bgn = nullptr;
  int n0, mi, si, n0n, min_, sin_;
  decode(ti, Ag, Bg, n0, mi, si);
  int tin = ti + gridDim.x;
  bool hasNext = tin < tiles;
  if (hasNext) decode(tin, Agn, Bgn, n0n, min_, sin_);

#define BAR()  asm volatile("" ::: "memory"); __builtin_amdgcn_s_barrier(); \
               asm volatile("" ::: "memory")

  stageH((const char*)Ag, 0, 0, 0);
  stageH((const char*)Bg, 0, 0, 32768);
  stageH((const char*)Ag, 0, 1, 0);
  stageH((const char*)Bg, 0, 1, 32768);
  asm volatile("s_waitcnt vmcnt(4)" ::: "memory");
  BAR();

  while (true) {
    f32x4 acc[8][4];
#pragma unroll
    for (int a = 0; a < 8; ++a)
#pragma unroll
      for (int bq = 0; bq < 4; ++bq)
#pragma unroll
        for (int e = 0; e < 4; ++e) acc[a][bq][e] = 0.f;

    float bv[2][2];
#pragma unroll
    for (int nh = 0; nh < 2; ++nh)
#pragma unroll
      for (int fn = 0; fn < 2; ++fn)
        bv[nh][fn] = bias[n0 + gn * 32 + nh * 128 + fn * 16 + fr];

#pragma unroll
    for (int ks = 0; ks < 8; ++ks) {
      const int bufB = (ks & 1) * 65536;
      const int nbufB = bufB ^ 65536;
      const bool st = (ks < 7) || hasNext;
      const char* pA = (ks < 7) ? (const char*)Ag : (const char*)Agn;
      const char* pB = (ks < 7) ? (const char*)Bg : (const char*)Bgn;
      const int kn = (ks < 7) ? ks + 1 : 0;
      bf16x8 af[2][4], b0[2][2], b1[2][2];

      // ===== phase 0 =====
#pragma unroll
      for (int fm = 0; fm < 4; ++fm) {
        af[0][fm] = ldf(bufB + aRowB + fm * 2048 + colk0);
        af[1][fm] = ldf(bufB + aRowB + fm * 2048 + colk1);
      }
#pragma unroll
      for (int fn = 0; fn < 2; ++fn) {
        b0[0][fn] = ldf(bufB + bRowB + fn * 2048 + colk0);
        b0[1][fn] = ldf(bufB + bRowB + fn * 2048 + colk1);
      }
      if (st) {
        stageH(pA, kn, 0, nbufB);
        asm volatile("s_waitcnt vmcnt(2)" ::: "memory");
      } else {
        asm volatile("s_waitcnt vmcnt(0)" ::: "memory");
      }
      BAR();
      __builtin_amdgcn_s_setprio(1);
#pragma unroll
      for (int kk = 0; kk < 2; ++kk)
#pragma unroll
        for (int fm = 0; fm < 4; ++fm)
#pragma unroll
          for (int fn = 0; fn < 2; ++fn)
            acc[fm][fn] = __builtin_amdgcn_mfma_f32_16x16x32_bf16(
                af[kk][fm], b0[kk][fn], acc[fm][fn], 0, 0, 0);
      __builtin_amdgcn_s_setprio(0);
      BAR();

      // ===== phase 1 =====
#pragma unroll
      for (int fn = 0; fn < 2; ++fn) {
        b1[0][fn] = ldf(bufB + bRowB + 16384 + fn * 2048 + colk0);
        b1[1][fn] = ldf(bufB + bRowB + 16384 + fn * 2048 + colk1);
      }
      if (st) stageH(pB, kn, 0, nbufB + 32768);
      BAR();
      __builtin_amdgcn_s_setprio(1);
#pragma unroll
      for (int kk = 0; kk < 2; ++kk)
#pragma unroll
        for (int fm = 0; fm < 4; ++fm)
#pragma unroll
          for (int fn = 0; fn < 2; ++fn)
            acc[fm][2 + fn] = __builtin_amdgcn_mfma_f32_16x16x32_bf16(
                af[kk][fm], b1[kk][fn], acc[fm][2 + fn], 0, 0, 0);
      __builtin_amdgcn_s_setprio(0);
      BAR();

      // ===== phase 2 =====
#pragma unroll
      for (int fm = 0; fm < 4; ++fm) {
        af[0][fm] = ldf(bufB + aRowB + 16384 + fm * 2048 + colk0);
        af[1][fm] = ldf(bufB + aRowB + 16384 + fm * 2048 + colk1);
      }
      if (st) stageH(pA, kn, 1, nbufB);
      BAR();
      __builtin_amdgcn_s_setprio(1);
#pragma unroll
      for (int kk = 0; kk < 2; ++kk)
#pragma unroll
        for (int fm = 0; fm < 4; ++fm)
#pragma unroll
          for (int fn = 0; fn < 2; ++fn)
            acc[4 + fm][2 + fn] = __builtin_amdgcn_mfma_f32_16x16x32_bf16(
                af[kk][fm], b1[kk][fn], acc[4 + fm][2 + fn], 0, 0, 0);
      __builtin_amdgcn_s_setprio(0);
      BAR();

      // ===== phase 3 =====
      if (st) stageH(pB, kn, 1, nbufB + 32768);
      BAR();
      __builtin_amdgcn_s_setprio(1);
#pragma unroll
      for (int kk = 0; kk < 2; ++kk)
#pragma unroll
        for (int fm = 0; fm < 4; ++fm)
#pragma unroll
          for (int fn = 0; fn < 2; ++fn)
            acc[4 + fm][fn] = __builtin_amdgcn_mfma_f32_16x16x32_bf16(
                af[kk][fm], b0[kk][fn], acc[4 + fm][fn], 0, 0, 0);
      __builtin_amdgcn_s_setprio(0);
      if (st) asm volatile("s_waitcnt vmcnt(4)" ::: "memory");
      BAR();
    }

    // epilogue: packed bf16x2 dword stores at perm5 positions
#pragma unroll
    for (int mh = 0; mh < 2; ++mh) {
#pragma unroll
      for (int fm = 0; fm < 4; ++fm) {
#pragma unroll
        for (int r = 0; r < 4; ++r) {
          int m = mi * 256 + gm * 64 + mh * 128 + fm * 16 + sgrp * 4 + r;
          int bl = m >> 10, t = m & 1023;
          size_t orow = (((size_t)bl * S_ + si) * T_ + t) * D_;
#pragma unroll
          for (int nh = 0; nh < 2; ++nh) {
            bf16x2 pk;
            pk[0] = (__bf16)(acc[mh * 4 + fm][nh * 2 + 0][r] + bv[nh][0]);
            pk[1] = (__bf16)(acc[mh * 4 + fm][nh * 2 + 1][r] + bv[nh][1]);
            int op = n0 + nh * 128 + gn * 32 + 2 * fr;
            *(bf16x2*)(xp + orow + op) = pk;
          }
        }
      }
    }

    if (!hasNext) break;
    ti = tin;
    Ag = Agn; Bg = Bgn; n0 = n0n; mi = min_; si = sin_;
    tin = ti + gridDim.x;
    hasNext = tin < tiles;
    if (hasNext) decode(tin, Agn, Bgn, n0n, min_, sin_);
  }
#undef BAR
}

// ---- predictions: LDS-staged A-panels, per-wave barrier-free pipeline ------
// Wave handles 2 tt. A-panel (12 rows x 1KB) staged in K-quarters (3KB) via
// 3 gld16, double-buffered; counted vmcnt(6); XOR swizzle (row&7)<<4 with
// inverse on the global source. B (y gather) direct from global as before.
__global__ __launch_bounds__(256) void pred_k(
    const unsigned short* __restrict__ xp,   // [bc][12][1024][512']
    const unsigned short* __restrict__ yT,   // [16][1024][512']
    const int* __restrict__ negs,            // [16][10][1024]
    float* __restrict__ preds, int b0, int do_labels) {
  __shared__ char plds[49152];   // 4 waves x [2 tt][2 buf][12 rows][256B]
  const int w = threadIdx.x >> 6, l = threadIdx.x & 63;
  const int bl = blockIdx.y;
  const int b = b0 + bl;
  const int fr = l & 15;
  const int sgrp = l >> 4;
  const int koff = sgrp * 8;                 // shorts, B-operand k-offset
  const int r_ld = l >> 4;                   // staging row-sub (0..3)
  const int c16 = l & 15;                    // staging 16B-slot within row

  int tts[2];
  const unsigned short* brow[2];
  const char* asrc[2][3];
#pragma unroll
  for (int q = 0; q < 2; ++q) {
    int tt = blockIdx.x * 4 + w + q * 512;
    tts[q] = tt;
    int j = tt;
    if (fr >= 1 && fr <= 10) j = negs[b * (10 * T_) + (fr - 1) * T_ + tt];
    brow[q] = yT + ((size_t)b * T_ + j) * D_;
#pragma unroll
    for (int i = 0; i < 3; ++i) {
      int r = i * 4 + r_ld;                  // panel row 0..11
      int t = tt - 1 - r;
      if (t < 0) t = 0;                      // clamped rows: results discarded
      asrc[q][i] = (const char*)(xp + (((size_t)bl * S_ + r) * T_ + t) * D_)
                   + ((c16 * 16) ^ ((r & 7) << 4));
    }
  }
  char* pbase = plds + w * 12288;            // wave-private 12KB

  auto stageQ = [&](int q, int qu, int buf) {
#pragma unroll
    for (int i = 0; i < 3; ++i)
      gld16(asrc[q][i] + qu * 256,
            pbase + (q * 2 + buf) * 3072 + i * 1024 + l * 16);
  };

  const int frc = (fr < S_) ? fr : 0;        // clamp A-read row
  const int swp = (frc & 7) << 4;
  const int arow0 = frc * 256;

  f32x4 acc[2];
#pragma unroll
  for (int q = 0; q < 2; ++q)
#pragma unroll
    for (int e = 0; e < 4; ++e) acc[q][e] = 0.f;

  // prologue: quarter 0 of both tt into buf 0 (6 gld16)
  stageQ(0, 0, 0);
  stageQ(1, 0, 0);

#pragma unroll
  for (int qu = 0; qu < 4; ++qu) {
    // drain this wave's ds_reads of the previous quarter before overwriting
    asm volatile("s_waitcnt lgkmcnt(0)" ::: "memory");
    if (qu < 3) {
      stageQ(0, qu + 1, (qu + 1) & 1);
      stageQ(1, qu + 1, (qu + 1) & 1);
      asm volatile("s_waitcnt vmcnt(6)" ::: "memory");   // quarter qu landed
    } else {
      asm volatile("s_waitcnt vmcnt(0)" ::: "memory");
    }
#pragma unroll
    for (int kq = 0; kq < 4; ++kq) {
      const int kk = qu * 4 + kq;
      const int acol = (sgrp * 16 + kq * 64) ^ swp;
#pragma unroll
      for (int q = 0; q < 2; ++q) {
        bf16x8 a = *(const bf16x8*)(pbase + (q * 2 + (qu & 1)) * 3072 +
                                    arow0 + acol);
        bf16x8 bb = *(const bf16x8*)(brow[q] + kk * 32 + koff);
        acc[q] = __builtin_amdgcn_mfma_f32_16x16x32_bf16(a, bb, acc[q], 0, 0, 0);
      }
    }
  }

#pragma unroll
  for (int q = 0; q < 2; ++q) {
#pragma unroll
    for (int r = 0; r < 4; ++r) {
      int ii = sgrp * 4 + r;
      int to = tts[q] - 1 - ii;
      if (ii < S_ && fr < C_ && tts[q] >= 1 && to >= 0) {
        int len = T_ - 1 - ii;
        preds[pred_base(ii) + ((size_t)fr * B_ + b) * len + to] = acc[q][r];
      }
    }
  }

  // ---- labels tail (grid-stride over out[P_TOTAL .. 2*P_TOTAL)) ----
  if (do_labels) {
    float* lab = preds + P_TOTAL;
    const int stride = gridDim.x * gridDim.y * 256;
    int k = (blockIdx.y * gridDim.x + blockIdx.x) * 256 + threadIdx.x;
    for (; k < P_TOTAL; k += stride) {
      int i = 0;
#pragma unroll
      for (int qq = 1; qq < 12; ++qq)
        if (k >= pred_base(qq)) i = qq;
      int rel = k - pred_base(i);
      int len = T_ - 1 - i;
      lab[k] = (rel < B_ * len) ? 1.0f : 0.0f;
    }
  }
}

extern "C" void kernel_launch(void* const* d_in, const int* in_sizes, int n_in,
                              void* d_out, int out_size, void* d_ws, size_t ws_size,
                              hipStream_t stream) {
  (void)in_sizes; (void)n_in; (void)out_size;
  const float* x = (const float*)d_in[0];
  const float* y = (const float*)d_in[1];
  const float* W = (const float*)d_in[2];
  const float* bias = (const float*)d_in[3];
  const int* negs = (const int*)d_in[4];
  float* out = (float*)d_out;
  char* ws = (char*)d_ws;

  unsigned short* wt = (unsigned short*)ws;                         // 6,291,456 B
  unsigned short* xb = (unsigned short*)(ws + 6291456);             // 16,777,216 B
  unsigned short* yT = (unsigned short*)(ws + 6291456 + 16777216);  // 16,777,216 B
  unsigned short* xp = (unsigned short*)(ws + 6291456 + 2 * 16777216);
  const size_t fixed = 6291456 + (size_t)2 * 16777216;              // 39,845,888
  const size_t xp_per_b = (size_t)S_ * T_ * D_ * 2;                 // 12,582,912
  int nb = 1;
  if (ws_size > fixed) {
    size_t cap = (ws_size - fixed) / xp_per_b;
    nb = cap < 1 ? 1 : (cap > 16 ? 16 : (int)cap);
  }

  hipLaunchKernelGGL(prep_w, dim3(16, 16), dim3(256), 0, stream, W, wt);
  hipLaunchKernelGGL(prep_t2, dim3(32, 16, 32), dim3(256), 0, stream, x, y, xb, yT);

  for (int b0 = 0; b0 < B_; b0 += nb) {
    int bc = (B_ - b0) < nb ? (B_ - b0) : nb;
    int tiles = bc * 4 * 2 * 12;              // 256x256 tiles
    int grid = tiles < 256 ? tiles : 256;
    hipLaunchKernelGGL(gemm_xp, dim3(grid), dim3(512), 0, stream,
                       xb + (size_t)b0 * T_ * D_, wt, bias, xp,
                       tiles, bc * 4);
    hipLaunchKernelGGL(pred_k, dim3(128, bc), dim3(256), 0, stream,
                       xp, yT, negs, out, b0, (int)(b0 == 0));
  }
}

// Round 13
// 192.086 us; speedup vs baseline: 4.8657x; 1.0107x over previous
//
#include <hip/hip_runtime.h>

typedef __bf16 bf16x8 __attribute__((ext_vector_type(8)));
typedef __bf16 bf16x2 __attribute__((ext_vector_type(2)));
typedef float f32x4 __attribute__((ext_vector_type(4)));

#define B_ 16
#define T_ 1024
#define D_ 512
#define S_ 12
#define C_ 11
static constexpr int P_TOTAL = 2148960;  // 176 * (12*1024 - 78)

__device__ __host__ inline constexpr int pred_base(int i) {
  return C_ * B_ * (T_ * i - (i * (i + 1)) / 2);
}

__device__ inline unsigned short f2bf(float f) {
  unsigned int u = __float_as_uint(f);
  u += 0x7FFF + ((u >> 16) & 1);   // round-to-nearest-even
  return (unsigned short)(u >> 16);
}

// low-5-bit storage permutation on the second-stage contraction dim
// (o of xp / d of x,y / i of W): natural v=(fn*16+fr) -> stored (fr<<1)|fn.
__device__ inline int perm5(int v) { return ((v & 15) << 1) | (v >> 4); }

__device__ inline void gld16(const void* g, void* l) {
  __builtin_amdgcn_global_load_lds(
      (const __attribute__((address_space(1))) void*)g,
      (__attribute__((address_space(3))) void*)l, 16, 0, 0);
}

// ---------------- prep: W [i][o][s] f32 -> wt [s][o][perm(i)] bf16 ----------
__global__ __launch_bounds__(256) void prep_w(const float* __restrict__ W,
                                              unsigned short* __restrict__ wt) {
  __shared__ unsigned short tile[32][33][12];
  const int i0 = blockIdx.x * 32, o0 = blockIdx.y * 32;
#pragma unroll
  for (int q = 0; q < 48; ++q) {
    int idx = threadIdx.x + q * 256;
    int ii = idx / 384, rem = idx % 384;
    tile[ii][rem / 12][rem % 12] =
        f2bf(W[(size_t)(i0 + ii) * 6144 + (size_t)o0 * 12 + rem]);
  }
  __syncthreads();
#pragma unroll
  for (int q = 0; q < 48; ++q) {
    int idx = threadIdx.x + q * 256;
    int ss = idx / 1024, rem = idx % 1024;
    int oo = rem / 32, ii = rem % 32;
    wt[(size_t)ss * (D_ * D_) + (size_t)(o0 + oo) * D_ + i0 + perm5(ii)] =
        tile[ii][oo][ss];
  }
}

// -- prep: transpose [b][D][T] f32 -> [b][T][perm(D)] bf16 (x and y, z=0..31) -
__global__ __launch_bounds__(256) void prep_t2(const float* __restrict__ xin,
                                               const float* __restrict__ yin,
                                               unsigned short* __restrict__ xo,
                                               unsigned short* __restrict__ yo) {
  __shared__ float tile[32][33];
  const int t0 = blockIdx.x * 32;
  const int d0 = blockIdx.y * 32;
  const int b = blockIdx.z & 15;
  const float* in = (blockIdx.z < 16) ? xin : yin;
  unsigned short* ob = (blockIdx.z < 16) ? xo : yo;
  const float* ib = in + (size_t)b * D_ * T_;
  const int r = threadIdx.x / 32, c = threadIdx.x % 32;
#pragma unroll
  for (int p = 0; p < 4; ++p) {
    int rr = r + p * 8;
    tile[rr][c] = ib[(size_t)(d0 + rr) * T_ + t0 + c];
  }
  __syncthreads();
  unsigned short* op = ob + (size_t)b * T_ * D_;
#pragma unroll
  for (int p = 0; p < 4; ++p) {
    int rr = r + p * 8;
    op[(size_t)(t0 + rr) * D_ + d0 + perm5(c)] = f2bf(tile[c][rr]);
  }
}

// ---- GEMM: xp[bl][s][t][perm(o)] = xb[m][i'] * wt[s][o][i'] + bias[o] ------
// R11 proven: 8-phase 256x256 / BK=64 / 8-wave, counted vmcnt, XOR swizzle,
// setprio, packed bf16x2 epilogue. 925 TF effective — concluded.
__global__ __launch_bounds__(512, 1) void gemm_xp(
    const unsigned short* __restrict__ xb,   // [bc*1024][512']
    const unsigned short* __restrict__ wt,   // [12][512 o][512 i']
    const float* __restrict__ bias,          // [512]
    unsigned short* __restrict__ xp,         // [bc][12][1024][512']
    int tiles, int mtiles) {
  __shared__ char ldsb[131072];  // 2 bufs x (A[256][64] 32KB + B[256][64] 32KB)
  const int tid = threadIdx.x;
  const int w = tid >> 6, l = tid & 63;
  const int gm = w >> 2, gn = w & 3;
  const int fr = l & 15, sgrp = l >> 4;

  const int dox0 = tid * 16, dox1 = tid * 16 + 8192;
  const int rl0 = dox0 >> 7, rl1 = dox1 >> 7;
  const int col = dox0 & 127;
  const int sco0 = rl0 * 1024 + (col ^ ((rl0 & 7) << 4));
  const int sco1 = rl1 * 1024 + (col ^ ((rl1 & 7) << 4));

  auto stageH = [&](const char* panel, int ks, int half, int ldsBase) {
    const char* s = panel + half * 131072 + ks * 128;
    char* d = ldsb + ldsBase + half * 16384;
    gld16(s + sco0, d + dox0);
    gld16(s + sco1, d + dox1);
  };

  const int sw = (fr & 7) << 4;
  const int colk0 = (sgrp * 16) ^ sw;
  const int colk1 = (64 + sgrp * 16) ^ sw;
  const int aRowB = (gm * 64 + fr) * 128;
  const int bRowB = 32768 + (gn * 32 + fr) * 128;

  auto ldf = [&](int off) -> bf16x8 {
    return *(const bf16x8*)(ldsb + off);
  };

  auto decode = [&](int t, const unsigned short*& Ag, const unsigned short*& Bg,
                    int& n0v, int& miv, int& siv) {
    miv = t % mtiles;
    int rest = t / mtiles;
    int ni = rest & 1;
    siv = rest >> 1;
    Ag = xb + (size_t)(miv * 256) * D_;
    Bg = wt + ((size_t)siv * D_ + ni * 256) * D_;
    n0v = ni * 256;
  };

  int ti = blockIdx.x;
  if (ti >= tiles) return;
  const unsigned short *Ag, *Bg, *Agn = nullptr, *Bgn = nullptr;
  int n0, mi, si, n0n, min_, sin_;
  decode(ti, Ag, Bg, n0, mi, si);
  int tin = ti + gridDim.x;
  bool hasNext = tin < tiles;
  if (hasNext) decode(tin, Agn, Bgn, n0n, min_, sin_);

#define BAR()  asm volatile("" ::: "memory"); __builtin_amdgcn_s_barrier(); \
               asm volatile("" ::: "memory")

  stageH((const char*)Ag, 0, 0, 0);
  stageH((const char*)Bg, 0, 0, 32768);
  stageH((const char*)Ag, 0, 1, 0);
  stageH((const char*)Bg, 0, 1, 32768);
  asm volatile("s_waitcnt vmcnt(4)" ::: "memory");
  BAR();

  while (true) {
    f32x4 acc[8][4];
#pragma unroll
    for (int a = 0; a < 8; ++a)
#pragma unroll
      for (int bq = 0; bq < 4; ++bq)
#pragma unroll
        for (int e = 0; e < 4; ++e) acc[a][bq][e] = 0.f;

    float bv[2][2];
#pragma unroll
    for (int nh = 0; nh < 2; ++nh)
#pragma unroll
      for (int fn = 0; fn < 2; ++fn)
        bv[nh][fn] = bias[n0 + gn * 32 + nh * 128 + fn * 16 + fr];

#pragma unroll
    for (int ks = 0; ks < 8; ++ks) {
      const int bufB = (ks & 1) * 65536;
      const int nbufB = bufB ^ 65536;
      const bool st = (ks < 7) || hasNext;
      const char* pA = (ks < 7) ? (const char*)Ag : (const char*)Agn;
      const char* pB = (ks < 7) ? (const char*)Bg : (const char*)Bgn;
      const int kn = (ks < 7) ? ks + 1 : 0;
      bf16x8 af[2][4], b0[2][2], b1[2][2];

      // ===== phase 0 =====
#pragma unroll
      for (int fm = 0; fm < 4; ++fm) {
        af[0][fm] = ldf(bufB + aRowB + fm * 2048 + colk0);
        af[1][fm] = ldf(bufB + aRowB + fm * 2048 + colk1);
      }
#pragma unroll
      for (int fn = 0; fn < 2; ++fn) {
        b0[0][fn] = ldf(bufB + bRowB + fn * 2048 + colk0);
        b0[1][fn] = ldf(bufB + bRowB + fn * 2048 + colk1);
      }
      if (st) {
        stageH(pA, kn, 0, nbufB);
        asm volatile("s_waitcnt vmcnt(2)" ::: "memory");
      } else {
        asm volatile("s_waitcnt vmcnt(0)" ::: "memory");
      }
      BAR();
      __builtin_amdgcn_s_setprio(1);
#pragma unroll
      for (int kk = 0; kk < 2; ++kk)
#pragma unroll
        for (int fm = 0; fm < 4; ++fm)
#pragma unroll
          for (int fn = 0; fn < 2; ++fn)
            acc[fm][fn] = __builtin_amdgcn_mfma_f32_16x16x32_bf16(
                af[kk][fm], b0[kk][fn], acc[fm][fn], 0, 0, 0);
      __builtin_amdgcn_s_setprio(0);
      BAR();

      // ===== phase 1 =====
#pragma unroll
      for (int fn = 0; fn < 2; ++fn) {
        b1[0][fn] = ldf(bufB + bRowB + 16384 + fn * 2048 + colk0);
        b1[1][fn] = ldf(bufB + bRowB + 16384 + fn * 2048 + colk1);
      }
      if (st) stageH(pB, kn, 0, nbufB + 32768);
      BAR();
      __builtin_amdgcn_s_setprio(1);
#pragma unroll
      for (int kk = 0; kk < 2; ++kk)
#pragma unroll
        for (int fm = 0; fm < 4; ++fm)
#pragma unroll
          for (int fn = 0; fn < 2; ++fn)
            acc[fm][2 + fn] = __builtin_amdgcn_mfma_f32_16x16x32_bf16(
                af[kk][fm], b1[kk][fn], acc[fm][2 + fn], 0, 0, 0);
      __builtin_amdgcn_s_setprio(0);
      BAR();

      // ===== phase 2 =====
#pragma unroll
      for (int fm = 0; fm < 4; ++fm) {
        af[0][fm] = ldf(bufB + aRowB + 16384 + fm * 2048 + colk0);
        af[1][fm] = ldf(bufB + aRowB + 16384 + fm * 2048 + colk1);
      }
      if (st) stageH(pA, kn, 1, nbufB);
      BAR();
      __builtin_amdgcn_s_setprio(1);
#pragma unroll
      for (int kk = 0; kk < 2; ++kk)
#pragma unroll
        for (int fm = 0; fm < 4; ++fm)
#pragma unroll
          for (int fn = 0; fn < 2; ++fn)
            acc[4 + fm][2 + fn] = __builtin_amdgcn_mfma_f32_16x16x32_bf16(
                af[kk][fm], b1[kk][fn], acc[4 + fm][2 + fn], 0, 0, 0);
      __builtin_amdgcn_s_setprio(0);
      BAR();

      // ===== phase 3 =====
      if (st) stageH(pB, kn, 1, nbufB + 32768);
      BAR();
      __builtin_amdgcn_s_setprio(1);
#pragma unroll
      for (int kk = 0; kk < 2; ++kk)
#pragma unroll
        for (int fm = 0; fm < 4; ++fm)
#pragma unroll
          for (int fn = 0; fn < 2; ++fn)
            acc[4 + fm][fn] = __builtin_amdgcn_mfma_f32_16x16x32_bf16(
                af[kk][fm], b0[kk][fn], acc[4 + fm][fn], 0, 0, 0);
      __builtin_amdgcn_s_setprio(0);
      if (st) asm volatile("s_waitcnt vmcnt(4)" ::: "memory");
      BAR();
    }

    // epilogue: packed bf16x2 dword stores at perm5 positions
#pragma unroll
    for (int mh = 0; mh < 2; ++mh) {
#pragma unroll
      for (int fm = 0; fm < 4; ++fm) {
#pragma unroll
        for (int r = 0; r < 4; ++r) {
          int m = mi * 256 + gm * 64 + mh * 128 + fm * 16 + sgrp * 4 + r;
          int bl = m >> 10, t = m & 1023;
          size_t orow = (((size_t)bl * S_ + si) * T_ + t) * D_;
#pragma unroll
          for (int nh = 0; nh < 2; ++nh) {
            bf16x2 pk;
            pk[0] = (__bf16)(acc[mh * 4 + fm][nh * 2 + 0][r] + bv[nh][0]);
            pk[1] = (__bf16)(acc[mh * 4 + fm][nh * 2 + 1][r] + bv[nh][1]);
            int op = n0 + nh * 128 + gn * 32 + 2 * fr;
            *(bf16x2*)(xp + orow + op) = pk;
          }
        }
      }
    }

    if (!hasNext) break;
    ti = tin;
    Ag = Agn; Bg = Bgn; n0 = n0n; mi = min_; si = sin_;
    tin = ti + gridDim.x;
    hasNext = tin < tiles;
    if (hasNext) decode(tin, Agn, Bgn, n0n, min_, sin_);
  }
#undef BAR
}

// ---- predictions: 1 tt per wave, LDS-staged A-panel, 24 waves/CU -----------
// Per wave: A-panel (12 rows) staged in K-quarters (3KB) via 3 gld16,
// double-buffered, counted vmcnt(3); XOR swizzle (row&7)<<4 with inverse on
// the global source. B (y gather) direct from global. 24 KB LDS/block ->
// 6 blocks/CU = 24 waves/CU (2x R12's TLP) to hide gather latency.
__global__ __launch_bounds__(256) void pred_k(
    const unsigned short* __restrict__ xp,   // [bc][12][1024][512']
    const unsigned short* __restrict__ yT,   // [16][1024][512']
    const int* __restrict__ negs,            // [16][10][1024]
    float* __restrict__ preds, int b0, int do_labels) {
  __shared__ char plds[24576];   // 4 waves x [2 buf][12 rows][256B]
  const int w = threadIdx.x >> 6, l = threadIdx.x & 63;
  const int bl = blockIdx.y;
  const int b = b0 + bl;
  const int fr = l & 15;
  const int sgrp = l >> 4;
  const int koff = sgrp * 8;                 // shorts, B-operand k-offset
  const int r_ld = l >> 4;                   // staging row-sub (0..3)
  const int c16 = l & 15;                    // staging 16B-slot within row

  const int tt = blockIdx.x * 4 + w;         // 0..1023
  int j = tt;
  if (fr >= 1 && fr <= 10) j = negs[b * (10 * T_) + (fr - 1) * T_ + tt];
  const unsigned short* brow = yT + ((size_t)b * T_ + j) * D_;

  const char* asrc[3];
#pragma unroll
  for (int i = 0; i < 3; ++i) {
    int r = i * 4 + r_ld;                    // panel row 0..11
    int t = tt - 1 - r;
    if (t < 0) t = 0;                        // clamped rows: results discarded
    asrc[i] = (const char*)(xp + (((size_t)bl * S_ + r) * T_ + t) * D_)
              + ((c16 * 16) ^ ((r & 7) << 4));
  }
  char* pbase = plds + w * 6144;             // wave-private 6KB (2 x 3KB)

  auto stageQ = [&](int qu, int buf) {
#pragma unroll
    for (int i = 0; i < 3; ++i)
      gld16(asrc[i] + qu * 256, pbase + buf * 3072 + i * 1024 + l * 16);
  };

  const int frc = (fr < S_) ? fr : 0;        // clamp A-read row
  const int swp = (frc & 7) << 4;
  const int arow0 = frc * 256;

  f32x4 acc;
#pragma unroll
  for (int e = 0; e < 4; ++e) acc[e] = 0.f;

  // prologue: quarter 0 into buf 0 (3 gld16)
  stageQ(0, 0);

#pragma unroll
  for (int qu = 0; qu < 4; ++qu) {
    // drain this wave's ds_reads of the previous quarter before overwriting
    asm volatile("s_waitcnt lgkmcnt(0)" ::: "memory");
    if (qu < 3) {
      stageQ(qu + 1, (qu + 1) & 1);
      asm volatile("s_waitcnt vmcnt(3)" ::: "memory");   // quarter qu landed
    } else {
      asm volatile("s_waitcnt vmcnt(0)" ::: "memory");
    }
#pragma unroll
    for (int kq = 0; kq < 4; ++kq) {
      const int kk = qu * 4 + kq;
      const int acol = (sgrp * 16 + kq * 64) ^ swp;
      bf16x8 a = *(const bf16x8*)(pbase + (qu & 1) * 3072 + arow0 + acol);
      bf16x8 bb = *(const bf16x8*)(brow + kk * 32 + koff);
      acc = __builtin_amdgcn_mfma_f32_16x16x32_bf16(a, bb, acc, 0, 0, 0);
    }
  }

#pragma unroll
  for (int r = 0; r < 4; ++r) {
    int ii = sgrp * 4 + r;
    int to = tt - 1 - ii;
    if (ii < S_ && fr < C_ && tt >= 1 && to >= 0) {
      int len = T_ - 1 - ii;
      preds[pred_base(ii) + ((size_t)fr * B_ + b) * len + to] = acc[r];
    }
  }

  // ---- labels tail (grid-stride over out[P_TOTAL .. 2*P_TOTAL)) ----
  if (do_labels) {
    float* lab = preds + P_TOTAL;
    const int stride = gridDim.x * gridDim.y * 256;
    int k = (blockIdx.y * gridDim.x + blockIdx.x) * 256 + threadIdx.x;
    for (; k < P_TOTAL; k += stride) {
      int i = 0;
#pragma unroll
      for (int qq = 1; qq < 12; ++qq)
        if (k >= pred_base(qq)) i = qq;
      int rel = k - pred_base(i);
      int len = T_ - 1 - i;
      lab[k] = (rel < B_ * len) ? 1.0f : 0.0f;
    }
  }
}

extern "C" void kernel_launch(void* const* d_in, const int* in_sizes, int n_in,
                              void* d_out, int out_size, void* d_ws, size_t ws_size,
                              hipStream_t stream) {
  (void)in_sizes; (void)n_in; (void)out_size;
  const float* x = (const float*)d_in[0];
  const float* y = (const float*)d_in[1];
  const float* W = (const float*)d_in[2];
  const float* bias = (const float*)d_in[3];
  const int* negs = (const int*)d_in[4];
  float* out = (float*)d_out;
  char* ws = (char*)d_ws;

  unsigned short* wt = (unsigned short*)ws;                         // 6,291,456 B
  unsigned short* xb = (unsigned short*)(ws + 6291456);             // 16,777,216 B
  unsigned short* yT = (unsigned short*)(ws + 6291456 + 16777216);  // 16,777,216 B
  unsigned short* xp = (unsigned short*)(ws + 6291456 + 2 * 16777216);
  const size_t fixed = 6291456 + (size_t)2 * 16777216;              // 39,845,888
  const size_t xp_per_b = (size_t)S_ * T_ * D_ * 2;                 // 12,582,912
  int nb = 1;
  if (ws_size > fixed) {
    size_t cap = (ws_size - fixed) / xp_per_b;
    nb = cap < 1 ? 1 : (cap > 16 ? 16 : (int)cap);
  }

  hipLaunchKernelGGL(prep_w, dim3(16, 16), dim3(256), 0, stream, W, wt);
  hipLaunchKernelGGL(prep_t2, dim3(32, 16, 32), dim3(256), 0, stream, x, y, xb, yT);

  for (int b0 = 0; b0 < B_; b0 += nb) {
    int bc = (B_ - b0) < nb ? (B_ - b0) : nb;
    int tiles = bc * 4 * 2 * 12;              // 256x256 tiles
    int grid = tiles < 256 ? tiles : 256;
    hipLaunchKernelGGL(gemm_xp, dim3(grid), dim3(512), 0, stream,
                       xb + (size_t)b0 * T_ * D_, wt, bias, xp,
                       tiles, bc * 4);
    hipLaunchKernelGGL(pred_k, dim3(256, bc), dim3(256), 0, stream,
                       xp, yT, negs, out, b0, (int)(b0 == 0));
  }
}